// Round 12
// baseline (70.262 us; speedup 1.0000x reference)
//
#include <hip/hip_runtime.h>
#include <math.h>
#include <stdint.h>

#define NN 2048   // nodes
#define IF 128    // in features
#define NH 4      // heads
#define NF 16     // hidden per head
#define OF 64     // NH*NF
#define JS 4      // j-split factor
#define JT 8      // j-tiles (of 64) per block = 512 j
#define NPB 16    // nodes per block (4 waves x 4 nodes)
#define PSTR 17   // partial stride: 16 acc + L
#define LOG2E 1.44269504f

typedef float f32x2 __attribute__((ext_vector_type(2)));
typedef float f32x4 __attribute__((ext_vector_type(4)));

__device__ __forceinline__ float rfl(float x) {   // force wave-uniform value into SGPR
    return __int_as_float(__builtin_amdgcn_readfirstlane(__float_as_int(x)));
}
__device__ __forceinline__ void gl2lds16(const void* g, void* l) {
    __builtin_amdgcn_global_load_lds((const __attribute__((address_space(1))) void*)g,
                                     (__attribute__((address_space(3))) void*)l, 16, 0, 0);
}
__device__ __forceinline__ void gl2lds4(const void* g, void* l) {
    __builtin_amdgcn_global_load_lds((const __attribute__((address_space(1))) void*)g,
                                     (__attribute__((address_space(3))) void*)l, 4, 0, 0);
}

// ---------------- Kernel 0: pack adjacency to bitmasks ----------------
__global__ __launch_bounds__(256) void pack_kernel(const int* __restrict__ adj,
                                                   uint32_t* __restrict__ bits) {
    const int w = threadIdx.x >> 6, lane = threadIdx.x & 63;
    const int i = blockIdx.x * 4 + w;
    const int* row = adj + (size_t)i * NN;
    uint64_t*  dst = (uint64_t*)bits + (size_t)i * 32;
    #pragma unroll 4
    for (int k = 0; k < 32; ++k) {
        const int v = row[k * 64 + lane];
        const uint64_t msk = __ballot(v != 0);
        if (lane == 0) dst[k] = msk;
    }
}

// ---------------- Kernel 1: projections (head-major) + softmax-bound precompute ----
// glt/grt [NH][NN][NF] head-major.
// cj6[h][j] = 0.6*L2E*(aw . gl_j)                       (per-j logit bias, base-2)
// cjB[h][j] = cj6[h][j] + 0.4*L2E*(|aw| . |gl_j|)       (upper-bound contribution)
// ai2[h][i] = 0.4*L2E*(|aw| . |gr_i|)                   (per-i bound; bi2 cancels!)
__global__ __launch_bounds__(256) void proj_kernel(const float* __restrict__ h,
                                                   const float* __restrict__ Wl,
                                                   const float* __restrict__ Wr,
                                                   const float* __restrict__ attn_w,
                                                   float* __restrict__ glt,
                                                   float* __restrict__ grt,
                                                   float* __restrict__ cj6,
                                                   float* __restrict__ cjB,
                                                   float* __restrict__ ai2) {
    const int t    = threadIdx.x;
    const int w    = t >> 6, lane = t & 63;
    const int il   = w >> 1, which = w & 1;          // which: 0 = W_l, 1 = W_r
    const int i    = blockIdx.x * 2 + il;

    __shared__ float hs[2][IF];
    hs[t >> 7][t & 127] = h[(blockIdx.x * 2 + (t >> 7)) * IF + (t & 127)];
    __syncthreads();

    const float* W = which ? Wr : Wl;
    float acc = 0.f;
    #pragma unroll
    for (int k = 0; k < IF; ++k)
        acc = fmaf(hs[il][k], W[k * OF + lane], acc);

    float* g = which ? grt : glt;
    g[(lane >> 4) * (NN * NF) + i * NF + (lane & 15)] = acc;

    const float awv = attn_w[lane & 15];
    float v  = acc * awv;
    float vb = fabsf(acc) * fabsf(awv);
    #pragma unroll
    for (int off = 1; off <= 8; off <<= 1) {
        v  += __shfl_xor(v,  off);
        vb += __shfl_xor(vb, off);
    }
    if ((lane & 15) == 0) {
        const int hh = lane >> 4;
        if (which) {
            ai2[hh * NN + i] = 0.4f * LOG2E * vb;
        } else {
            const float c2 = 0.6f * LOG2E * v;
            cj6[hh * NN + i] = c2;
            cjB[hh * NN + i] = fmaf(0.4f * LOG2E, vb, c2);
        }
    }
}

// ---------------- Kernel 1b: per-head max of cjB (softmax bound) ----------------
__global__ __launch_bounds__(256) void mh_kernel(const float* __restrict__ cjB,
                                                 float* __restrict__ mh) {
    const int hh = blockIdx.x, t = threadIdx.x;
    float mx = -INFINITY;
    for (int j = t; j < NN; j += 256) mx = fmaxf(mx, cjB[hh * NN + j]);
    #pragma unroll
    for (int off = 32; off; off >>= 1) mx = fmaxf(mx, __shfl_xor(mx, off));
    __shared__ float wmx[4];
    if ((t & 63) == 0) wmx[t >> 6] = mx;
    __syncthreads();
    if (t == 0) mh[hh] = fmaxf(fmaxf(wmx[0], wmx[1]), fmaxf(wmx[2], wmx[3]));
}

// ---------------- Kernel 2: fused flash GAT, static softmax bound, JS=4 ----------------
// grid JS*128*NH = 2048 (8 blocks/CU budget; LDS 26KB -> 6 resident), block 256
// (4 waves), 4 nodes/wave, head h, 512 j's per block. Static softmax shift
// (no online max); j-split partials merged by plain add in reduce_kernel.
__global__ __launch_bounds__(256) __attribute__((amdgpu_waves_per_eu(2, 4)))
void gat_kernel(const float* __restrict__ glt,
                const float* __restrict__ grt,
                const float* __restrict__ cj6,
                const float* __restrict__ ai2,
                const float* __restrict__ mh,
                const uint32_t* __restrict__ bits,
                const float* __restrict__ attn_w,
                float* __restrict__ part) {
    const int t    = threadIdx.x;
    const int wid  = t >> 6, lane = t & 63;
    const int h    = blockIdx.x & 3;
    const int grp  = (blockIdx.x >> 2) & 127;
    const int s    = blockIdx.x >> 9;                 // j-split quarter (0..3)

    __shared__ __attribute__((aligned(16))) float g_s[2][64 * NF];   // swizzled tiles
    __shared__ __attribute__((aligned(16))) float r_s[2][64 * NF];
    __shared__ uint32_t bits_s[NPB * 16];             // 16 nodes x 16 words (512 j bits)
    __shared__ float    c_all[JT * 64];               // all cj for this j-range
    __shared__ float    red[4][16][NF + 1];

    // ---- prologue staging (once): bits (1KB) + cj (2KB) ----
    {
        const int idx = wid * 64 + lane;              // node = idx>>4, word = idx&15
        gl2lds4(bits + ((size_t)(grp * 16 + (idx >> 4))) * 64 + s * 16 + (idx & 15),
                (char*)bits_s + (wid * 64) * 4);
    }
    {
        const float* cjh = cj6 + h * NN + s * (JT * 64);
        #pragma unroll
        for (int k = 0; k < 2; ++k)
            gl2lds4(cjh + k * 256 + wid * 64 + lane,
                    (char*)c_all + (k * 256 + wid * 64) * 4);
    }

    // ---- wave-uniform constants -> SGPR ----
    float aw_s[NF];
    #pragma unroll
    for (int f = 0; f < NF; ++f) aw_s[f] = rfl(attn_w[f]) * (0.4f * LOG2E);
    const float mh_s = rfl(mh[h]);
    float gi_s[4][NF], cni[4];
    #pragma unroll
    for (int n = 0; n < 4; ++n) {
        const int i_n = grp * 16 + wid * 4 + n;
        #pragma unroll
        for (int f = 0; f < NF; ++f)
            gi_s[n][f] = rfl(grt[h * (NN * NF) + i_n * NF + f]);
        cni[n] = -(rfl(ai2[h * NN + i_n]) + mh_s);    // static softmax shift (SGPR)
    }

    const float* glh = glt + (size_t)h * NN * NF + (size_t)s * JT * 64 * NF;
    const float* grh = grt + (size_t)h * NN * NF + (size_t)s * JT * 64 * NF;

    // staging geometry (source-side XOR swizzle; read XOR undoes it, verified r6-r11)
    const int soff = (wid * 16 + (lane >> 2)) * NF + (((lane & 3) ^ ((lane >> 3) & 3)) << 2);

#define STAGE(tile, nb)                                                   \
    {                                                                     \
        gl2lds16(glh + (size_t)(tile) * 64 * NF + soff, &g_s[nb][wid * 16 * NF]); \
        gl2lds16(grh + (size_t)(tile) * 64 * NF + soff, &r_s[nb][wid * 16 * NF]); \
    }

    float l[4];
    f32x2 acc[4][8];
    #pragma unroll
    for (int n = 0; n < 4; ++n) {
        l[n] = 0.f;
        #pragma unroll
        for (int k = 0; k < 8; ++k) acc[n][k] = (f32x2){0.f, 0.f};
    }

    STAGE(0, 0);
    __syncthreads();

    const int sh = lane & 31;
    #pragma unroll 2
    for (int tt = 0; tt < JT; ++tt) {
        const int buf = tt & 1;
        if (tt + 1 < JT) STAGE(tt + 1, buf ^ 1);

        // ---- scores (scalar: gi in SGPR keeps VGPR ~72); rv kept for PV ----
        f32x4 rv[4];
        float ss[4] = {0.f, 0.f, 0.f, 0.f};
        #pragma unroll
        for (int q = 0; q < 4; ++q) {
            const int c = q ^ ((lane >> 1) & 3);
            const f32x4 gv = *(const f32x4*)&g_s[buf][lane * NF + c * 4];
            rv[q] = *(const f32x4*)&r_s[buf][lane * NF + c * 4];
            #pragma unroll
            for (int n = 0; n < 4; ++n) {
                ss[n] = fmaf(fabsf(gv[0] + gi_s[n][q * 4 + 0]), aw_s[q * 4 + 0], ss[n]);
                ss[n] = fmaf(fabsf(gv[1] + gi_s[n][q * 4 + 1]), aw_s[q * 4 + 1], ss[n]);
                ss[n] = fmaf(fabsf(gv[2] + gi_s[n][q * 4 + 2]), aw_s[q * 4 + 2], ss[n]);
                ss[n] = fmaf(fabsf(gv[3] + gi_s[n][q * 4 + 3]), aw_s[q * 4 + 3], ss[n]);
            }
        }
        const float cj = c_all[tt * 64 + lane];

        // ---- softmax weights: p = exp2(ss + cj + cni) or 0 if masked ----
        float p[4];
        #pragma unroll
        for (int n = 0; n < 4; ++n) {
            const uint32_t wb = bits_s[(wid * 4 + n) * 16 + tt * 2 + (lane >> 5)];
            const bool  kk = ((wb >> sh) & 1u) != 0u;
            float e = (ss[n] + cj) + cni[n];
            e = kk ? e : -INFINITY;                    // exp2(-inf) = 0
            const float pp = __builtin_amdgcn_exp2f(e);
            l[n] += pp;
            p[n] = pp;
        }

        // ---- PV: packed v_pk_fma_f32 ----
        #pragma unroll
        for (int q = 0; q < 4; ++q) {
            const f32x2 lo = {rv[q][0], rv[q][1]};
            const f32x2 hi = {rv[q][2], rv[q][3]};
            #pragma unroll
            for (int n = 0; n < 4; ++n) {
                const f32x2 pp2 = {p[n], p[n]};
                acc[n][q * 2 + 0] = __builtin_elementwise_fma(pp2, lo, acc[n][q * 2 + 0]);
                acc[n][q * 2 + 1] = __builtin_elementwise_fma(pp2, hi, acc[n][q * 2 + 1]);
            }
        }
        __syncthreads();   // drains stage(t+1) + protects buffer swap
    }
#undef STAGE

    // ---- epilogue: merge across 64 lanes (no max rescale), write partials ----
    #pragma unroll
    for (int n = 0; n < 4; ++n) {
        float L = l[n];
        #pragma unroll
        for (int off = 32; off; off >>= 1) L += __shfl_xor(L, off);

        #pragma unroll
        for (int f = 0; f < NF; ++f) {
            float a = acc[n][f >> 1][f & 1];
            a += __shfl_xor(a, 32);
            a += __shfl_xor(a, 16);
            if (lane < 16) red[wid][lane][f] = a;     // wave-private slab, no barrier
        }
        const int i_n = grp * 16 + wid * 4 + n;
        float* P = part + ((size_t)s * NH * NN + (size_t)h * NN + i_n) * PSTR;
        if (lane < NF) {
            float a = 0.f;
            #pragma unroll
            for (int r = 0; r < 16; ++r) a += red[wid][r][lane];
            P[lane] = a;
        } else if (lane == 16) P[16] = L;
    }
}

// ---------------- Kernel 3: merge j-split partials (same static m -> plain add) ----
__global__ __launch_bounds__(256) void reduce_kernel(const float* __restrict__ part,
                                                     float* __restrict__ out) {
    const int c  = blockIdx.x * 256 + threadIdx.x;    // 131072 = 2048*4*16
    const int f  = c & 15;
    const int ih = c >> 4;                            // h*NN + i
    float L = 0.f, a = 0.f;
    #pragma unroll
    for (int ss = 0; ss < JS; ++ss) {
        const float* P = part + ((size_t)ss * NH * NN + ih) * PSTR;
        a += P[f];
        L += P[16];
    }
    const float o = (L > 0.f) ? a / L : 0.f;          // L==0 -> nan_to_num(0)
    const int i = ih & (NN - 1);
    const int h = ih >> 11;
    out[(size_t)i * OF + h * NF + f] = o;
}

extern "C" void kernel_launch(void* const* d_in, const int* in_sizes, int n_in,
                              void* d_out, int out_size, void* d_ws, size_t ws_size,
                              hipStream_t stream) {
    const float* h      = (const float*)d_in[0];
    const int*   adj    = (const int*)d_in[1];
    const float* W_l    = (const float*)d_in[2];
    const float* W_r    = (const float*)d_in[3];
    const float* attn_w = (const float*)d_in[4];
    float*       out    = (float*)d_out;

    float*    glt  = (float*)d_ws;                        // [NH][NN][NF] 512KB
    float*    grt  = glt + (size_t)NN * OF;               // [NH][NN][NF] 512KB
    float*    cj6  = grt + (size_t)NN * OF;               // [NH][NN] 32KB
    float*    cjB  = cj6 + (size_t)NH * NN;               // [NH][NN] 32KB
    float*    ai2  = cjB + (size_t)NH * NN;               // [NH][NN] 32KB
    float*    mh   = ai2 + (size_t)NH * NN;               // [NH] (+pad)
    uint32_t* bits = (uint32_t*)(mh + 64);                // [NN][64w] 512KB
    float*    prt  = (float*)(bits + (size_t)NN * 64);    // [JS][NH*NN][17] ~2.2MB

    pack_kernel<<<NN / 4, 256, 0, stream>>>(adj, bits);
    proj_kernel<<<NN / 2, 256, 0, stream>>>(h, W_l, W_r, attn_w, glt, grt, cj6, cjB, ai2);
    mh_kernel<<<NH, 256, 0, stream>>>(cjB, mh);
    gat_kernel<<<JS * 128 * NH, 256, 0, stream>>>(glt, grt, cj6, ai2, mh, bits, attn_w, prt);
    reduce_kernel<<<NH * NN * NF / 256, 256, 0, stream>>>(prt, out);
}

// Round 13
// 60.739 us; speedup vs baseline: 1.1568x; 1.1568x over previous
//
#include <hip/hip_runtime.h>
#include <math.h>
#include <stdint.h>

#define NN 2048   // nodes
#define IF 128    // in features
#define NH 4      // heads
#define NF 16     // hidden per head
#define OF 64     // NH*NF
#define JS 2      // j-split factor
#define JT 16     // j-tiles (of 64) per block = 1024 j
#define NPW 2     // nodes per wave
#define NPB 8     // nodes per block (4 waves x 2 nodes)
#define PSTR 17   // partial stride: 16 acc + L
#define LOG2E 1.44269504f

// LDS layout (bytes):                                 size
//   0     : tile g[buf0]                               4096
//   4096  : tile g[buf1]                               4096
//   8192  : tile r[buf0]                               4096
//   12288 : tile r[buf1]                               4096
//   16384 : bits_s  (8 nodes x 32 words)               1024
//   17408 : c_s[2][64]                                  512
//   total                                             17920  -> 8 blocks/CU fit
//   epilogue: red[4][16][17] aliases bytes 0..4351 (tiles dead after loop)

typedef float f32x2 __attribute__((ext_vector_type(2)));
typedef float f32x4 __attribute__((ext_vector_type(4)));

__device__ __forceinline__ float rfl(float x) {   // force wave-uniform value into SGPR
    return __int_as_float(__builtin_amdgcn_readfirstlane(__float_as_int(x)));
}
__device__ __forceinline__ void gl2lds16(const void* g, void* l) {
    __builtin_amdgcn_global_load_lds((const __attribute__((address_space(1))) void*)g,
                                     (__attribute__((address_space(3))) void*)l, 16, 0, 0);
}
__device__ __forceinline__ void gl2lds4(const void* g, void* l) {
    __builtin_amdgcn_global_load_lds((const __attribute__((address_space(1))) void*)g,
                                     (__attribute__((address_space(3))) void*)l, 4, 0, 0);
}

// ---------------- Kernel 0: pack adjacency to bitmasks ----------------
__global__ __launch_bounds__(256) void pack_kernel(const int* __restrict__ adj,
                                                   uint32_t* __restrict__ bits) {
    const int w = threadIdx.x >> 6, lane = threadIdx.x & 63;
    const int i = blockIdx.x * 4 + w;
    const int* row = adj + (size_t)i * NN;
    uint64_t*  dst = (uint64_t*)bits + (size_t)i * 32;
    #pragma unroll 4
    for (int k = 0; k < 32; ++k) {
        const int v = row[k * 64 + lane];
        const uint64_t msk = __ballot(v != 0);
        if (lane == 0) dst[k] = msk;
    }
}

// ---------------- Kernel 1: projections (head-major) + softmax-bound precompute ----
__global__ __launch_bounds__(256) void proj_kernel(const float* __restrict__ h,
                                                   const float* __restrict__ Wl,
                                                   const float* __restrict__ Wr,
                                                   const float* __restrict__ attn_w,
                                                   float* __restrict__ glt,
                                                   float* __restrict__ grt,
                                                   float* __restrict__ cj6,
                                                   float* __restrict__ cjB,
                                                   float* __restrict__ ai2) {
    const int t    = threadIdx.x;
    const int w    = t >> 6, lane = t & 63;
    const int il   = w >> 1, which = w & 1;          // which: 0 = W_l, 1 = W_r
    const int i    = blockIdx.x * 2 + il;

    __shared__ float hs[2][IF];
    hs[t >> 7][t & 127] = h[(blockIdx.x * 2 + (t >> 7)) * IF + (t & 127)];
    __syncthreads();

    const float* W = which ? Wr : Wl;
    float acc = 0.f;
    #pragma unroll
    for (int k = 0; k < IF; ++k)
        acc = fmaf(hs[il][k], W[k * OF + lane], acc);

    float* g = which ? grt : glt;
    g[(lane >> 4) * (NN * NF) + i * NF + (lane & 15)] = acc;

    const float awv = attn_w[lane & 15];
    float v  = acc * awv;
    float vb = fabsf(acc) * fabsf(awv);
    #pragma unroll
    for (int off = 1; off <= 8; off <<= 1) {
        v  += __shfl_xor(v,  off);
        vb += __shfl_xor(vb, off);
    }
    if ((lane & 15) == 0) {
        const int hh = lane >> 4;
        if (which) {
            ai2[hh * NN + i] = 0.4f * LOG2E * vb;
        } else {
            const float c2 = 0.6f * LOG2E * v;
            cj6[hh * NN + i] = c2;
            cjB[hh * NN + i] = fmaf(0.4f * LOG2E, vb, c2);
        }
    }
}

// ---------------- Kernel 1b: per-head max of cjB (softmax bound) ----------------
__global__ __launch_bounds__(256) void mh_kernel(const float* __restrict__ cjB,
                                                 float* __restrict__ mh) {
    const int hh = blockIdx.x, t = threadIdx.x;
    float mx = -INFINITY;
    for (int j = t; j < NN; j += 256) mx = fmaxf(mx, cjB[hh * NN + j]);
    #pragma unroll
    for (int off = 32; off; off >>= 1) mx = fmaxf(mx, __shfl_xor(mx, off));
    __shared__ float wmx[4];
    if ((t & 63) == 0) wmx[t >> 6] = mx;
    __syncthreads();
    if (t == 0) mh[hh] = fmaxf(fmaxf(wmx[0], wmx[1]), fmaxf(wmx[2], wmx[3]));
}

// ---------------- Kernel 2: fused flash GAT, 2 nodes/wave, 64-VGPR shape ----------------
// grid JS*256*NH = 2048 (8 blocks/CU x 4 waves = 32 waves/CU), block 256.
// 2 nodes/wave (acc 32 VGPR) + transient rv (PV reads r-tile per-q AFTER exp) keeps
// peak VGPR <= 64 -> 8 waves/SIMD (the occupancy boundary: waves halve at 64/128/256).
// Static softmax shift (no online max); j-split partials merged by plain add.
__global__ __launch_bounds__(256) __attribute__((amdgpu_waves_per_eu(2, 8)))
void gat_kernel(const float* __restrict__ glt,
                const float* __restrict__ grt,
                const float* __restrict__ cj6,
                const float* __restrict__ ai2,
                const float* __restrict__ mh,
                const uint32_t* __restrict__ bits,
                const float* __restrict__ attn_w,
                float* __restrict__ part) {
    const int t    = threadIdx.x;
    const int wid  = t >> 6, lane = t & 63;
    const int h    = blockIdx.x & 3;
    const int grp  = (blockIdx.x >> 2) & 255;
    const int s    = blockIdx.x >> 10;                // j-split half

    __shared__ __attribute__((aligned(16))) char smem[17920];
    float*    tile   = (float*)smem;                  // g: buf*1024; r: 2048 + buf*1024 (floats)
    uint32_t* bits_s = (uint32_t*)(smem + 16384);
    float*    c_s    = (float*)(smem + 17408);

    // ---- prologue staging (once): bits (1KB) ----
    {
        const int idx = wid * 64 + lane;              // node = idx>>5, word = idx&31
        gl2lds4(bits + ((size_t)(grp * 8 + (idx >> 5))) * 64 + s * 32 + (idx & 31),
                smem + 16384 + wid * 256);
    }

    // ---- wave-uniform constants -> SGPR ----
    float aw_s[NF];
    #pragma unroll
    for (int f = 0; f < NF; ++f) aw_s[f] = rfl(attn_w[f]) * (0.4f * LOG2E);
    const float mh_s = rfl(mh[h]);
    float gi_s[NPW][NF], cni[NPW];
    #pragma unroll
    for (int n = 0; n < NPW; ++n) {
        const int i_n = grp * NPB + wid * NPW + n;
        #pragma unroll
        for (int f = 0; f < NF; ++f)
            gi_s[n][f] = rfl(grt[h * (NN * NF) + i_n * NF + f]);
        cni[n] = -(rfl(ai2[h * NN + i_n]) + mh_s);    // static softmax shift (SGPR)
    }

    const float* glh = glt + (size_t)h * NN * NF + (size_t)s * JT * 64 * NF;
    const float* grh = grt + (size_t)h * NN * NF + (size_t)s * JT * 64 * NF;
    const float* cjh = cj6 + h * NN + s * (JT * 64);

    // staging geometry (source-side XOR swizzle; read XOR undoes it, verified r6-r12)
    const int soff = (wid * 16 + (lane >> 2)) * NF + (((lane & 3) ^ ((lane >> 3) & 3)) << 2);

#define STAGE(tl, nb)                                                              \
    {                                                                              \
        gl2lds16(glh + (size_t)(tl) * (64 * NF) + soff, smem + (nb) * 4096 + wid * 1024);        \
        gl2lds16(grh + (size_t)(tl) * (64 * NF) + soff, smem + 8192 + (nb) * 4096 + wid * 1024); \
        if (wid == 0) gl2lds4(cjh + (tl) * 64 + lane, smem + 17408 + (nb) * 256);  \
    }

    float l[NPW];
    f32x2 acc[NPW][8];
    #pragma unroll
    for (int n = 0; n < NPW; ++n) {
        l[n] = 0.f;
        #pragma unroll
        for (int k = 0; k < 8; ++k) acc[n][k] = (f32x2){0.f, 0.f};
    }

    STAGE(0, 0);
    __syncthreads();

    const int sh   = lane & 31;
    const int csw  = (lane >> 1) & 3;                 // read-side de-swizzle XOR
    #pragma unroll 2
    for (int tt = 0; tt < JT; ++tt) {
        const int buf = tt & 1;
        if (tt + 1 < JT) STAGE(tt + 1, buf ^ 1);

        // ---- phase 1: scores (gv transient per q) ----
        float ss[NPW] = {0.f, 0.f};
        #pragma unroll
        for (int q = 0; q < 4; ++q) {
            const int c = q ^ csw;
            const f32x4 gv = *(const f32x4*)&tile[buf * 1024 + lane * NF + c * 4];
            #pragma unroll
            for (int n = 0; n < NPW; ++n) {
                ss[n] = fmaf(fabsf(gv[0] + gi_s[n][q * 4 + 0]), aw_s[q * 4 + 0], ss[n]);
                ss[n] = fmaf(fabsf(gv[1] + gi_s[n][q * 4 + 1]), aw_s[q * 4 + 1], ss[n]);
                ss[n] = fmaf(fabsf(gv[2] + gi_s[n][q * 4 + 2]), aw_s[q * 4 + 2], ss[n]);
                ss[n] = fmaf(fabsf(gv[3] + gi_s[n][q * 4 + 3]), aw_s[q * 4 + 3], ss[n]);
            }
        }
        const float cj = c_s[buf * 64 + lane];

        // ---- phase 2: softmax weights p = exp2(ss + cj + cni) or 0 if masked ----
        float p[NPW];
        #pragma unroll
        for (int n = 0; n < NPW; ++n) {
            const uint32_t wb = bits_s[(wid * NPW + n) * 32 + tt * 2 + (lane >> 5)];
            const bool  kk = ((wb >> sh) & 1u) != 0u;
            float e = (ss[n] + cj) + cni[n];
            e = kk ? e : -INFINITY;                    // exp2(-inf) = 0
            const float pp = __builtin_amdgcn_exp2f(e);
            l[n] += pp;
            p[n] = pp;
        }

        // ---- phase 3: PV, rv transient per q (keeps peak VGPR <= 64) ----
        #pragma unroll
        for (int q = 0; q < 4; ++q) {
            const int c = q ^ csw;
            const f32x4 rv = *(const f32x4*)&tile[2048 + buf * 1024 + lane * NF + c * 4];
            const f32x2 lo = {rv[0], rv[1]};
            const f32x2 hi = {rv[2], rv[3]};
            #pragma unroll
            for (int n = 0; n < NPW; ++n) {
                const f32x2 pp2 = {p[n], p[n]};
                acc[n][q * 2 + 0] = __builtin_elementwise_fma(pp2, lo, acc[n][q * 2 + 0]);
                acc[n][q * 2 + 1] = __builtin_elementwise_fma(pp2, hi, acc[n][q * 2 + 1]);
            }
        }
        __syncthreads();   // drains stage(t+1) + protects buffer swap
    }
#undef STAGE

    // ---- epilogue: merge across 64 lanes, write partials. red aliases tile space
    // (all waves passed the final loop barrier -> tiles dead; red slabs wave-private).
    float (*red)[16][PSTR] = (float (*)[16][PSTR])smem;   // [4][16][17]
    #pragma unroll
    for (int n = 0; n < NPW; ++n) {
        float L = l[n];
        #pragma unroll
        for (int off = 32; off; off >>= 1) L += __shfl_xor(L, off);

        #pragma unroll
        for (int f = 0; f < NF; ++f) {
            float a = acc[n][f >> 1][f & 1];
            a += __shfl_xor(a, 32);
            a += __shfl_xor(a, 16);
            if (lane < 16) red[wid][lane][f] = a;     // wave-private slab, no barrier
        }
        const int i_n = grp * NPB + wid * NPW + n;
        float* P = part + ((size_t)s * NH * NN + (size_t)h * NN + i_n) * PSTR;
        if (lane < NF) {
            float a = 0.f;
            #pragma unroll
            for (int r = 0; r < 16; ++r) a += red[wid][r][lane];
            P[lane] = a;
        } else if (lane == 16) P[16] = L;
    }
}

// ---------------- Kernel 3: merge j-split partials (same static m -> plain add) ----
__global__ __launch_bounds__(256) void reduce_kernel(const float* __restrict__ part,
                                                     float* __restrict__ out) {
    const int c  = blockIdx.x * 256 + threadIdx.x;    // 131072 = 2048*4*16
    const int f  = c & 15;
    const int ih = c >> 4;                            // h*NN + i
    float L = 0.f, a = 0.f;
    #pragma unroll
    for (int ss = 0; ss < JS; ++ss) {
        const float* P = part + ((size_t)ss * NH * NN + ih) * PSTR;
        a += P[f];
        L += P[16];
    }
    const float o = (L > 0.f) ? a / L : 0.f;          // L==0 -> nan_to_num(0)
    const int i = ih & (NN - 1);
    const int h = ih >> 11;
    out[(size_t)i * OF + h * NF + f] = o;
}

extern "C" void kernel_launch(void* const* d_in, const int* in_sizes, int n_in,
                              void* d_out, int out_size, void* d_ws, size_t ws_size,
                              hipStream_t stream) {
    const float* h      = (const float*)d_in[0];
    const int*   adj    = (const int*)d_in[1];
    const float* W_l    = (const float*)d_in[2];
    const float* W_r    = (const float*)d_in[3];
    const float* attn_w = (const float*)d_in[4];
    float*       out    = (float*)d_out;

    float*    glt  = (float*)d_ws;                        // [NH][NN][NF] 512KB
    float*    grt  = glt + (size_t)NN * OF;               // [NH][NN][NF] 512KB
    float*    cj6  = grt + (size_t)NN * OF;               // [NH][NN] 32KB
    float*    cjB  = cj6 + (size_t)NH * NN;               // [NH][NN] 32KB
    float*    ai2  = cjB + (size_t)NH * NN;               // [NH][NN] 32KB
    float*    mh   = ai2 + (size_t)NH * NN;               // [NH] (+pad)
    uint32_t* bits = (uint32_t*)(mh + 64);                // [NN][64w] 512KB
    float*    prt  = (float*)(bits + (size_t)NN * 64);    // [JS][NH*NN][17] ~1.1MB

    pack_kernel<<<NN / 4, 256, 0, stream>>>(adj, bits);
    proj_kernel<<<NN / 2, 256, 0, stream>>>(h, W_l, W_r, attn_w, glt, grt, cj6, cjB, ai2);
    mh_kernel<<<NH, 256, 0, stream>>>(cjB, mh);
    gat_kernel<<<JS * 256 * NH, 256, 0, stream>>>(glt, grt, cj6, ai2, mh, bits, attn_w, prt);
    reduce_kernel<<<NH * NN * NF / 256, 256, 0, stream>>>(prt, out);
}